// Round 1
// baseline (36566.000 us; speedup 1.0000x reference)
//
#include <hip/hip_runtime.h>
#include <math.h>

#define NBLK 256
#define NTHR 256

#define B_ 128
#define T_ 512
#define U_ 128
#define N_ 80
#define H_ 512
#define M_ 10
#define K_ 595      // 3 + 80 + 512
#define CC_ 16      // z-cols per block (4 h-units x 4 gates)
#define CH_ 32      // K-chunk rows
#define NCH_ 19     // ceil(595/32)

// ---------------- hierarchical grid barrier (monotonic epochs) ----------------
// bar layout (uints): grp[g] at g*32 (g<16), root at 512, release at 544. Zeroed by host memset.
__device__ __forceinline__ void gbar(unsigned* bar, unsigned epoch) {
    __syncthreads();
    if (threadIdx.x == 0) {
        __threadfence();                       // agent-scope release (flushes to coherence point)
        unsigned g = blockIdx.x & 15u;
        unsigned old = atomicAdd(&bar[g * 32], 1u);
        if (old + 1u == epoch * 16u) {         // 16th block of this group, this epoch
            unsigned ro = atomicAdd(&bar[512], 1u);
            if (ro + 1u == epoch * 16u) {      // all 16 groups closed
                __hip_atomic_store(&bar[544], epoch, __ATOMIC_RELEASE, __HIP_MEMORY_SCOPE_AGENT);
            }
        }
        while (__hip_atomic_load(&bar[544], __ATOMIC_RELAXED, __HIP_MEMORY_SCOPE_AGENT) < epoch) {
            __builtin_amdgcn_s_sleep(2);
        }
        __threadfence();                       // agent-scope acquire
    }
    __syncthreads();
}

__global__ __launch_bounds__(NTHR) void rnn_kernel(
    const float* __restrict__ strokes, const float* __restrict__ trans,
    const float* __restrict__ Wx, const float* __restrict__ Wh,
    const float* __restrict__ bias, const float* __restrict__ Wd,
    const float* __restrict__ bd, float* __restrict__ out,
    float* __restrict__ hbuf, unsigned* __restrict__ bar) {

    // ---- LDS (total 62.5 KB, <64 KB -> 2 blocks/CU capacity => no barrier deadlock) ----
    __shared__ __align__(16) float Wl[K_ * CC_];        // 38080 B, persistent weight slice
    __shared__ __align__(16) float inpT[2][CH_ * 64];   // 16384 B, double-buffered input chunks [k][b]
    __shared__ float zbuf[64 * 17];                     // 4352 B, padded stride 17 (bank-conflict-free)
    __shared__ float cst[64 * 4];                       // c-state [b][jl]
    __shared__ float kap[M_];                           // kappa carry (stage-B blocks)
    __shared__ float yl[30];
    __shared__ float wf[U_ + 1];
    __shared__ float avv[256];
    __shared__ int   avi[256];

    const int tid = threadIdx.x;
    const int bid = blockIdx.x;
    const int bg  = bid >> 7;     // batch half: batches [bg*64, bg*64+64)
    const int hs  = bid & 127;    // h-slice: h-units [hs*4, hs*4+4)

    float* wbufT = hbuf + 2 * H_ * B_;   // w carry, layout [n][b]

    // ---- load persistent weight slice: Wl[k*16+cc], cc=g*4+jl -> col g*512+hs*4+jl ----
    for (int idx = tid; idx < K_ * CC_; idx += NTHR) {
        int k = idx >> 4, cc = idx & 15;
        int col = (cc >> 2) * 512 + hs * 4 + (cc & 3);
        Wl[idx] = (k < 83) ? Wx[k * 2048 + col] : Wh[(k - 83) * 2048 + col];
    }
    for (int i = tid; i < 64 * 4; i += NTHR) cst[i] = 0.f;
    if (tid < M_) kap[tid] = 0.f;
    // zero global carry state (hbuf[2][512][128] + wbufT[80][128], contiguous)
    for (int i = bid * NTHR + tid; i < 2 * H_ * B_ + N_ * B_; i += NBLK * NTHR) hbuf[i] = 0.f;

    unsigned epoch = 1;
    gbar(bar, epoch);

    // GEMM thread mapping: 4 batches x 2 cols x K-split-2
    const int bg4 = tid & 15;          // batch group (4 batches)
    const int ks  = (tid >> 4) & 1;    // K parity (lane bit 4 -> shfl_xor 16)
    const int cg  = tid >> 5;          // col pair (8 pairs = 16 cols)
    const int lane = tid & 63;
    const int rw   = tid >> 6;         // wave id (row stride 4 in staging)

    for (int t = 0; t < T_; ++t) {
        const float* hR = hbuf + (t & 1) * (H_ * B_);
        float* hW = hbuf + ((t + 1) & 1) * (H_ * B_);

        float acc[4][2] = {{0.f,0.f},{0.f,0.f},{0.f,0.f},{0.f,0.f}};

        // ---- preload chunk 0 (k = 0..31: x rows then w rows) ----
        for (int r = rw; r < CH_; r += 4) {
            float v;
            if (r < 3) v = strokes[(size_t)(bg * 64 + lane) * (T_ * 3) + t * 3 + r];
            else       v = wbufT[(r - 3) * B_ + bg * 64 + lane];
            inpT[0][r * 64 + lane] = v;
        }
        __syncthreads();

        for (int c = 0; c < NCH_; ++c) {
            const int k0 = c * CH_;
            const int kn = (K_ - k0 < CH_) ? (K_ - k0) : CH_;
            const int cb = c & 1;
            // issue next chunk into the other buffer (overlaps with compute)
            if (c + 1 < NCH_) {
                const int nk0 = k0 + CH_;
                const int nkn = (K_ - nk0 < CH_) ? (K_ - nk0) : CH_;
                for (int r = rw; r < nkn; r += 4) {
                    int k = nk0 + r;
                    float v;
                    if (k < 83) v = wbufT[(k - 3) * B_ + bg * 64 + lane];   // nk0>=32 so k>=3 always
                    else        v = hR[(k - 83) * B_ + bg * 64 + lane];
                    inpT[cb ^ 1][r * 64 + lane] = v;
                }
            }
            // compute on buffer cb
            const float* ib = inpT[cb];
            #pragma unroll 4
            for (int k = ks; k < kn; k += 2) {
                float4 iv = *(const float4*)&ib[k * 64 + bg4 * 4];
                float2 wv = *(const float2*)&Wl[(k0 + k) * CC_ + cg * 2];
                acc[0][0] = fmaf(iv.x, wv.x, acc[0][0]); acc[0][1] = fmaf(iv.x, wv.y, acc[0][1]);
                acc[1][0] = fmaf(iv.y, wv.x, acc[1][0]); acc[1][1] = fmaf(iv.y, wv.y, acc[1][1]);
                acc[2][0] = fmaf(iv.z, wv.x, acc[2][0]); acc[2][1] = fmaf(iv.z, wv.y, acc[2][1]);
                acc[3][0] = fmaf(iv.w, wv.x, acc[3][0]); acc[3][1] = fmaf(iv.w, wv.y, acc[3][1]);
            }
            __syncthreads();
        }

        // ---- cross-K reduce (lane bit 4) and stash z ----
        #pragma unroll
        for (int bb = 0; bb < 4; ++bb)
            #pragma unroll
            for (int ci = 0; ci < 2; ++ci) {
                float v = acc[bb][ci];
                v += __shfl_xor(v, 16, 64);
                if (ks == 0) zbuf[(bg4 * 4 + bb) * 17 + cg * 2 + ci] = v;
            }
        __syncthreads();

        // ---- LSTM pointwise: thread = (b, jl) ----
        {
            int b = tid & 63, jl = tid >> 6;
            float zi = zbuf[b * 17 + jl];
            float zf = zbuf[b * 17 + 4 + jl];
            float zg = zbuf[b * 17 + 8 + jl];
            float zo = zbuf[b * 17 + 12 + jl];
            int colb = hs * 4 + jl;
            zi += bias[colb]; zf += bias[512 + colb]; zg += bias[1024 + colb]; zo += bias[1536 + colb];
            float co = cst[b * 4 + jl];
            float si = 1.f / (1.f + expf(-zi));
            float sf = 1.f / (1.f + expf(-zf));
            float so = 1.f / (1.f + expf(-zo));
            float cn = sf * co + si * tanhf(zg);
            float hn = so * tanhf(cn);
            cst[b * 4 + jl] = cn;
            hW[(hs * 4 + jl) * B_ + bg * 64 + b] = hn;
        }

        ++epoch; gbar(bar, epoch);   // h_t visible grid-wide

        // ---- stage B: attention + outputs, one block per batch ----
        if (bid < B_) {
            const int b = bid;
            if (tid < 240) {                       // y = h @ Wd : 30 cols x 8-lane segments
                int col = tid >> 3, seg = tid & 7;
                float s = 0.f;
                int j = seg * 64;
                #pragma unroll 4
                for (int jj = 0; jj < 64; ++jj, ++j)
                    s = fmaf(hW[j * B_ + b], Wd[j * 30 + col], s);
                s += __shfl_down(s, 4, 8);
                s += __shfl_down(s, 2, 8);
                s += __shfl_down(s, 1, 8);
                if (seg == 0) yl[col] = s;
            }
            __syncthreads();
            if (tid < 30) {
                float e = expf(yl[tid] + bd[tid]);
                yl[tid] = e;
                if (tid >= 20) kap[tid - 20] += e;  // kappa carry
            }
            __syncthreads();
            if (tid <= U_) {                        // wfull[u], u = 0..128
                float u = (float)tid, s = 0.f;
                #pragma unroll
                for (int m = 0; m < M_; ++m) {
                    float d = kap[m] - u;
                    s += yl[m] * expf(-yl[10 + m] * d * d);
                }
                wf[tid] = s;
            }
            __syncthreads();
            // argmax, np first-max semantics (contiguous halves, strict >)
            avv[tid] = (tid <= U_) ? wf[tid] : -INFINITY;
            avi[tid] = tid;
            __syncthreads();
            for (int s2 = 128; s2 >= 1; s2 >>= 1) {
                if (tid < s2) {
                    if (avv[tid + s2] > avv[tid]) { avv[tid] = avv[tid + s2]; avi[tid] = avi[tid + s2]; }
                }
                __syncthreads();
            }
            float* op = out + ((size_t)b * T_ + t) * 593;
            for (int j = tid; j < H_; j += NTHR) op[j] = hW[j * B_ + b];
            if (tid < N_) {                        // w = wfull[:128] @ trans[b]
                float s = 0.f;
                const float* tp = trans + (size_t)b * (U_ * N_) + tid;
                #pragma unroll 4
                for (int u = 0; u < U_; ++u) s = fmaf(wf[u], tp[u * N_], s);
                op[512 + tid] = s;
                wbufT[tid * B_ + b] = s;
            }
            if (tid == 0) op[592] = (float)avi[0];
        }

        ++epoch; gbar(bar, epoch);   // w_t visible grid-wide
    }
}

extern "C" void kernel_launch(void* const* d_in, const int* in_sizes, int n_in,
                              void* d_out, int out_size, void* d_ws, size_t ws_size,
                              hipStream_t stream) {
    const float* strokes = (const float*)d_in[0];
    const float* trans   = (const float*)d_in[1];
    // d_in[2] = enumerated (arange, recomputed in-kernel)
    const float* Wx      = (const float*)d_in[3];
    const float* Wh      = (const float*)d_in[4];
    const float* bias    = (const float*)d_in[5];
    const float* Wd      = (const float*)d_in[6];
    const float* bd      = (const float*)d_in[7];
    float* out = (float*)d_out;

    unsigned* bar = (unsigned*)d_ws;                     // 4 KB barrier state
    float* hbuf = (float*)((char*)d_ws + 4096);          // h ping-pong (512KB) + w carry (40KB)

    hipMemsetAsync(d_ws, 0, 4096, stream);               // reset barrier epochs (ws is poisoned)
    hipLaunchKernelGGL(rnn_kernel, dim3(NBLK), dim3(NTHR), 0, stream,
                       strokes, trans, Wx, Wh, bias, Wd, bd, out, hbuf, bar);
}

// Round 2
// 27793.176 us; speedup vs baseline: 1.3156x; 1.3156x over previous
//
#include <hip/hip_runtime.h>
#include <math.h>

#define NBLK 256
#define NTHR 256
#define HB 64      // batches per half
#define T_ 512
#define U_ 128
#define N_ 80
#define H_ 512
#define M_ 10
#define KTOT 595   // K order: [h 0..511][w 0..79][x 0..2]

typedef __attribute__((address_space(1))) const unsigned int* gp1_t;
typedef __attribute__((address_space(3))) unsigned int* lp3_t;
// width-16 global->LDS DMA: lane i writes ldsbase + i*16, reads gptr + i*16
#define GLOAD16(gp, lp) __builtin_amdgcn_global_load_lds((gp1_t)(gp), (lp3_t)(lp), 16, 0, 0)

__global__ __launch_bounds__(NTHR) void rnn_kernel(
    const float* __restrict__ strokes, const float* __restrict__ trans,
    const float* __restrict__ Wx, const float* __restrict__ Wh,
    const float* __restrict__ bias, const float* __restrict__ Wd,
    const float* __restrict__ bd, float* __restrict__ out,
    float* __restrict__ hbuf, float* __restrict__ wbufT, float* __restrict__ hT,
    unsigned* __restrict__ cnt) {

    // LDS ~61.8 KB (<64 KB static)
    __shared__ __align__(16) float Wl[KTOT * 16];      // 38080 B weight slice, permuted K order
    __shared__ __align__(16) float inpT[2][32 * 64];   // 16384 B dbuf input chunks [k][b]
    __shared__ __align__(16) float zbuf[64 * 20];      // 5120 B z / reused as h-column in stage B
    __shared__ float cst[256];                         // c-state [b][jl]
    __shared__ float kap[M_];
    __shared__ float yl[30];
    __shared__ float wf[U_ + 1];
    __shared__ float avv[64];
    __shared__ int   avi[64];

    const int tid  = threadIdx.x;
    const int bid  = blockIdx.x;
    const int half = bid >> 7;     // batch half
    const int hs   = bid & 127;    // h-slice: h-units hs*4..hs*4+3
    const int lane = tid & 63;
    const int rw   = tid >> 6;     // wave id = col-group (gate)
    const int bg4  = lane & 15;    // batch group of 4
    const int ks   = lane >> 4;    // K-split 4 (lane bits 4-5)
    const int cg4  = rw * 4;
    const int bg44 = bg4 * 4;

    unsigned* hcnt = cnt + half * 32;        // h-ready: +128 per step
    unsigned* wcnt = cnt + 64 + half * 32;   // w-ready: +64 per step
    float* wT_half = wbufT + half * (N_ * HB);

    // ---- init: weights (permuted K), zero state ----
    for (int idx = tid; idx < KTOT * 16; idx += NTHR) {
        int kk = idx >> 4, cc = idx & 15;
        int col = (cc >> 2) * 512 + hs * 4 + (cc & 3);   // gate*512 + h-unit
        float v;
        if (kk < 512)      v = Wh[kk * 2048 + col];
        else if (kk < 592) v = Wx[(3 + kk - 512) * 2048 + col];
        else               v = Wx[(kk - 592) * 2048 + col];
        Wl[idx] = v;
    }
    for (int i = tid; i < 256; i += NTHR) cst[i] = 0.f;
    if (tid < M_) kap[tid] = 0.f;
    for (int i = bid * NTHR + tid; i < 2 * H_ * HB + 2 * N_ * HB; i += NBLK * NTHR) {
        if (i < 2 * H_ * HB) hbuf[i] = 0.f;            // parity-0 h = 0
        else wbufT[i - 2 * H_ * HB] = 0.f;             // w_{-1} = 0
    }
    __syncthreads();
    if (tid == 0) {                                    // one-time flat init barrier
        __threadfence();
        atomicAdd(&cnt[128], 1u);
        while (__hip_atomic_load(&cnt[128], __ATOMIC_RELAXED, __HIP_MEMORY_SCOPE_AGENT) < (unsigned)NBLK)
            __builtin_amdgcn_s_sleep(1);
        __threadfence();
    }
    __syncthreads();

    const bool isB = (hs & 1) == 0;                    // 64 stage-B blocks per half
    const int  bB  = half * HB + (hs >> 1);            // its batch

    for (int t = 0; t < T_; ++t) {
        const float* hR = hbuf + ((t & 1) * 2 + half) * (H_ * HB);
        float*       hW = hbuf + (((t + 1) & 1) * 2 + half) * (H_ * HB);

        // ---- wait h_{t-1} (per-half) ----
        if (tid == 0) {
            while (__hip_atomic_load(hcnt, __ATOMIC_RELAXED, __HIP_MEMORY_SCOPE_AGENT) < 128u * (unsigned)t)
                __builtin_amdgcn_s_sleep(1);
            __threadfence();
        }
        __syncthreads();

        float acc[4][4];
        #pragma unroll
        for (int a = 0; a < 4; ++a)
            #pragma unroll
            for (int b2 = 0; b2 < 4; ++b2) acc[a][b2] = 0.f;

        // stage chunk 0 (h rows 0..31): 2 DMA issues per wave, 4 rows each
        {
            const float* src = hR;
            float* dst = &inpT[0][0];
            GLOAD16(src + rw * 256 + lane * 4, dst + rw * 256);
            GLOAD16(src + (rw + 4) * 256 + lane * 4, dst + (rw + 4) * 256);
        }
        __syncthreads();

        for (int c = 0; c < 19; ++c) {
            if (c + 1 < 19) {
                if (c + 1 == 16) {        // w rows start: need w_{t-1}
                    if (tid == 0) {
                        while (__hip_atomic_load(wcnt, __ATOMIC_RELAXED, __HIP_MEMORY_SCOPE_AGENT) < 64u * (unsigned)t)
                            __builtin_amdgcn_s_sleep(1);
                        __threadfence();
                    }
                    __syncthreads();
                }
                const int tc = c + 1;
                float* dst = &inpT[tc & 1][0];
                if (tc < 16) {
                    const float* src = hR + tc * 2048;
                    GLOAD16(src + rw * 256 + lane * 4, dst + rw * 256);
                    GLOAD16(src + (rw + 4) * 256 + lane * 4, dst + (rw + 4) * 256);
                } else if (tc < 18) {
                    const float* src = wT_half + (tc - 16) * 2048;
                    GLOAD16(src + rw * 256 + lane * 4, dst + rw * 256);
                    GLOAD16(src + (rw + 4) * 256 + lane * 4, dst + (rw + 4) * 256);
                } else {
                    const float* src = wT_half + 64 * 64;    // w rows 64..79
                    GLOAD16(src + rw * 256 + lane * 4, dst + rw * 256);
                    if (tid < 192) {                          // x rows 16..18
                        int r = tid >> 6;
                        dst[(16 + r) * 64 + lane] =
                            strokes[(size_t)(half * HB + lane) * (T_ * 3) + t * 3 + r];
                    }
                }
            }
            // ---- compute chunk c: 4b x 4c per thread, K interleaved 4-way ----
            const float* ib = &inpT[c & 1][0];
            const float* wl = &Wl[c * 32 * 16];
            if (c < 18) {
                #pragma unroll
                for (int i = 0; i < 8; ++i) {
                    int k = 4 * i + ks;
                    float4 iv = *(const float4*)(ib + k * 64 + bg44);
                    float4 wv = *(const float4*)(wl + k * 16 + cg4);
                    acc[0][0] = fmaf(iv.x, wv.x, acc[0][0]); acc[0][1] = fmaf(iv.x, wv.y, acc[0][1]);
                    acc[0][2] = fmaf(iv.x, wv.z, acc[0][2]); acc[0][3] = fmaf(iv.x, wv.w, acc[0][3]);
                    acc[1][0] = fmaf(iv.y, wv.x, acc[1][0]); acc[1][1] = fmaf(iv.y, wv.y, acc[1][1]);
                    acc[1][2] = fmaf(iv.y, wv.z, acc[1][2]); acc[1][3] = fmaf(iv.y, wv.w, acc[1][3]);
                    acc[2][0] = fmaf(iv.z, wv.x, acc[2][0]); acc[2][1] = fmaf(iv.z, wv.y, acc[2][1]);
                    acc[2][2] = fmaf(iv.z, wv.z, acc[2][2]); acc[2][3] = fmaf(iv.z, wv.w, acc[2][3]);
                    acc[3][0] = fmaf(iv.w, wv.x, acc[3][0]); acc[3][1] = fmaf(iv.w, wv.y, acc[3][1]);
                    acc[3][2] = fmaf(iv.w, wv.z, acc[3][2]); acc[3][3] = fmaf(iv.w, wv.w, acc[3][3]);
                }
            } else {
                for (int i = 0; i < 5; ++i) {
                    int k = 4 * i + ks;
                    if (k < 19) {
                        float4 iv = *(const float4*)(ib + k * 64 + bg44);
                        float4 wv = *(const float4*)(wl + k * 16 + cg4);
                        acc[0][0] = fmaf(iv.x, wv.x, acc[0][0]); acc[0][1] = fmaf(iv.x, wv.y, acc[0][1]);
                        acc[0][2] = fmaf(iv.x, wv.z, acc[0][2]); acc[0][3] = fmaf(iv.x, wv.w, acc[0][3]);
                        acc[1][0] = fmaf(iv.y, wv.x, acc[1][0]); acc[1][1] = fmaf(iv.y, wv.y, acc[1][1]);
                        acc[1][2] = fmaf(iv.y, wv.z, acc[1][2]); acc[1][3] = fmaf(iv.y, wv.w, acc[1][3]);
                        acc[2][0] = fmaf(iv.z, wv.x, acc[2][0]); acc[2][1] = fmaf(iv.z, wv.y, acc[2][1]);
                        acc[2][2] = fmaf(iv.z, wv.z, acc[2][2]); acc[2][3] = fmaf(iv.z, wv.w, acc[2][3]);
                        acc[3][0] = fmaf(iv.w, wv.x, acc[3][0]); acc[3][1] = fmaf(iv.w, wv.y, acc[3][1]);
                        acc[3][2] = fmaf(iv.w, wv.z, acc[3][2]); acc[3][3] = fmaf(iv.w, wv.w, acc[3][3]);
                    }
                }
            }
            __syncthreads();
        }

        // ---- cross-K reduce (lane bits 4,5) + stash z ----
        #pragma unroll
        for (int bb = 0; bb < 4; ++bb) {
            #pragma unroll
            for (int cc2 = 0; cc2 < 4; ++cc2) {
                float v = acc[bb][cc2];
                v += __shfl_xor(v, 16, 64);
                v += __shfl_xor(v, 32, 64);
                acc[bb][cc2] = v;
            }
            if (ks == 0)
                *(float4*)&zbuf[(bg44 + bb) * 20 + cg4] =
                    make_float4(acc[bb][0], acc[bb][1], acc[bb][2], acc[bb][3]);
        }
        __syncthreads();

        // ---- LSTM pointwise: thread = (b, jl) ----
        {
            int b = tid & 63, jl = tid >> 6;
            int colb = hs * 4 + jl;
            float zi = zbuf[b * 20 + 0  + jl] + bias[colb];
            float zf = zbuf[b * 20 + 4  + jl] + bias[512 + colb];
            float zg = zbuf[b * 20 + 8  + jl] + bias[1024 + colb];
            float zo = zbuf[b * 20 + 12 + jl] + bias[1536 + colb];
            float co = cst[b * 4 + jl];
            float si = 1.f / (1.f + expf(-zi));
            float sf = 1.f / (1.f + expf(-zf));
            float so = 1.f / (1.f + expf(-zo));
            float cn = sf * co + si * tanhf(zg);
            float hn = so * tanhf(cn);
            cst[b * 4 + jl] = cn;
            hW[colb * 64 + b] = hn;                             // [j][b] for GEMM staging
            hT[(size_t)(half * HB + b) * 512 + colb] = hn;      // [b][j] for stage B
        }
        __syncthreads();
        if (tid == 0) { __threadfence(); atomicAdd(hcnt, 1u); }  // release h_t

        // ---- stage B: attention, overlapped with other blocks' next GEMM ----
        if (isB) {
            if (tid == 0) {
                while (__hip_atomic_load(hcnt, __ATOMIC_RELAXED, __HIP_MEMORY_SCOPE_AGENT) < 128u * (unsigned)(t + 1))
                    __builtin_amdgcn_s_sleep(1);
                __threadfence();
            }
            __syncthreads();
            if (tid < 128)   // coalesced 2KB h-column load
                ((float4*)zbuf)[tid] = ((const float4*)(hT + (size_t)bB * 512))[tid];
            __syncthreads();
            if (tid < 240) {                       // y = h @ Wd : 30 cols x 8 segs
                int col = tid >> 3, seg = tid & 7;
                const float* hp = zbuf + seg * 64;
                const float* wdp = Wd + (size_t)seg * 64 * 30 + col;
                float s = 0.f;
                #pragma unroll 8
                for (int jj = 0; jj < 64; ++jj) s = fmaf(hp[jj], wdp[jj * 30], s);
                s += __shfl_down(s, 4, 8);
                s += __shfl_down(s, 2, 8);
                s += __shfl_down(s, 1, 8);
                if (seg == 0) yl[col] = s;
            }
            __syncthreads();
            if (tid < 30) {
                float e = expf(yl[tid] + bd[tid]);
                yl[tid] = e;
                if (tid >= 20) kap[tid - 20] += e;
            }
            __syncthreads();
            if (tid <= U_) {
                float u = (float)tid, s = 0.f;
                #pragma unroll
                for (int m = 0; m < M_; ++m) {
                    float d = kap[m] - u;
                    s += yl[m] * expf(-yl[10 + m] * d * d);
                }
                wf[tid] = s;
            }
            __syncthreads();
            if (tid < 64) {                        // argmax (np first-max; ties measure-zero)
                float v = wf[tid]; int ii = tid;
                float v2 = wf[tid + 64];
                if (v2 > v) { v = v2; ii = tid + 64; }
                avv[tid] = v; avi[tid] = ii;
            }
            __syncthreads();
            for (int s2 = 32; s2 >= 1; s2 >>= 1) {
                if (tid < s2) {
                    if (avv[tid + s2] > avv[tid]) { avv[tid] = avv[tid + s2]; avi[tid] = avi[tid + s2]; }
                }
                __syncthreads();
            }
            float* op = out + ((size_t)bB * T_ + t) * 593;
            for (int j = tid; j < H_; j += NTHR) op[j] = zbuf[j];   // coalesced h out
            if (tid < N_) {                        // w = wfull[:128] @ trans[b]
                const float* tp = trans + (size_t)bB * (U_ * N_) + tid;
                float s = 0.f;
                #pragma unroll 4
                for (int u = 0; u < U_; ++u) s = fmaf(wf[u], tp[u * N_], s);
                op[512 + tid] = s;
                wT_half[tid * 64 + (bB & 63)] = s;
            }
            if (tid == 0) {
                float v = avv[0]; int ii = avi[0];
                if (wf[128] > v) ii = 128;         // fold index 128 (strict >)
                op[592] = (float)ii;
            }
            __syncthreads();
            if (tid == 0) { __threadfence(); atomicAdd(wcnt, 1u); }  // release w_t
        }
    }
}

extern "C" void kernel_launch(void* const* d_in, const int* in_sizes, int n_in,
                              void* d_out, int out_size, void* d_ws, size_t ws_size,
                              hipStream_t stream) {
    const float* strokes = (const float*)d_in[0];
    const float* trans   = (const float*)d_in[1];
    // d_in[2] = enumerated (arange, recomputed in-kernel)
    const float* Wx      = (const float*)d_in[3];
    const float* Wh      = (const float*)d_in[4];
    const float* bias    = (const float*)d_in[5];
    const float* Wd      = (const float*)d_in[6];
    const float* bd      = (const float*)d_in[7];
    float* out = (float*)d_out;

    unsigned* cnt = (unsigned*)d_ws;                       // 4 KB counters
    float* hbuf  = (float*)((char*)d_ws + 4096);           // [par][half][512][64] 512 KB
    float* wbufT = hbuf + 2 * 2 * H_ * HB;                 // [half][80][64] 40 KB
    float* hT    = wbufT + 2 * N_ * HB;                    // [128][512] 256 KB

    hipMemsetAsync(d_ws, 0, 4096, stream);                 // reset counters (ws is poisoned)
    hipLaunchKernelGGL(rnn_kernel, dim3(NBLK), dim3(NTHR), 0, stream,
                       strokes, trans, Wx, Wh, bias, Wd, bd, out, hbuf, wbufT, hT, cnt);
}